// Round 1
// baseline (312.609 us; speedup 1.0000x reference)
//
#include <hip/hip_runtime.h>

// Problem constants (match reference)
#define XD 256
#define YD 256
#define ZD 16
#define TD 5
#define BD 2
#define NP 300000
#define CMID 8
#define VPB (XD * YD * ZD * TD)      // 5,242,880 voxels per batch
#define NVOX (BD * VPB)              // 10,485,760 total voxels
#define OCC_WORDS (NVOX / 32)        // 327,680 uint32 words (1.31 MB)

// ---------------------------------------------------------------------------
// Kernel 1: scatter points -> bit-packed occupancy grid
// ---------------------------------------------------------------------------
__global__ __launch_bounds__(256) void scatter_occ_kernel(
    const float4* __restrict__ pts, unsigned int* __restrict__ occ) {
    int i = blockIdx.x * 256 + threadIdx.x;
    if (i >= BD * NP) return;
    float4 p = pts[i];  // (x, y, z, t)
    // Match JAX: floor(p / quant) then clip to [0, dim-1]
    int cx = min(max((int)floorf(p.x / 0.4f), 0), XD - 1);
    int cy = min(max((int)floorf(p.y / 0.4f), 0), YD - 1);
    int cz = min(max((int)floorf(p.z / 0.4f), 0), ZD - 1);
    int ct = min(max((int)floorf(p.w / 1.0f), 0), TD - 1);
    int b  = i / NP;
    int lin = (((cx * YD) + cy) * ZD + cz) * TD + ct + b * VPB;
    atomicOr(&occ[lin >> 5], 1u << (lin & 31));  // idempotent -> deterministic
}

// ---------------------------------------------------------------------------
// Kernel 2: per-voxel 81-tap conv + ReLU + 8->1 projection, masked by occ.
// Output nonzero only at occupied voxels (reference multiplies by mask twice).
// grid = 0.5 * occ exactly, and 0.5*sum(w) == sum(0.5*w) exactly in fp32,
// so we accumulate raw W0 rows and scale by 0.5 at the end.
// ---------------------------------------------------------------------------
__global__ __launch_bounds__(256) void conv_kernel(
    const unsigned int* __restrict__ occ,
    const float* __restrict__ W0,   // (81, 1, 8)
    const float* __restrict__ b0,   // (8)
    const float* __restrict__ W1,   // (8, 1)
    const float* __restrict__ b1,   // (1)
    float* __restrict__ out) {      // (B, 1, X, Y, Z, T) == voxel-linear
    __shared__ float w0s[81 * CMID];
    __shared__ float b0s[CMID];
    __shared__ float w1s[CMID];
    __shared__ float b1s;
    for (int j = threadIdx.x; j < 81 * CMID; j += 256) w0s[j] = W0[j];
    if (threadIdx.x < CMID) {
        b0s[threadIdx.x] = b0[threadIdx.x];
        w1s[threadIdx.x] = W1[threadIdx.x];
    }
    if (threadIdx.x == 0) b1s = b1[0];
    __syncthreads();

    int idx = blockIdx.x * 256 + threadIdx.x;  // grid sized exactly NVOX
    // Self-occupancy: unoccupied voxels output exactly 0 (mask gating).
    if (!((occ[idx >> 5] >> (idx & 31)) & 1u)) {
        out[idx] = 0.0f;
        return;
    }

    int t = idx % TD;
    int zrem = idx / TD;
    int z = zrem % ZD;
    int yrem = zrem / ZD;
    int y = yrem % YD;
    int xrem = yrem / YD;
    int x = xrem % XD;
    int base_b = (idx / VPB) * VPB;

    float h[CMID];
#pragma unroll
    for (int c = 0; c < CMID; ++c) h[c] = 0.0f;

    // k = (((dx+1)*3 + (dy+1))*3 + (dz+1))*3 + (dt+1), dt fastest (ref order)
    for (int dx = -1; dx <= 1; ++dx) {
        int nx = x + dx;
        if ((unsigned)nx >= XD) continue;
        for (int dy = -1; dy <= 1; ++dy) {
            int ny = y + dy;
            if ((unsigned)ny >= YD) continue;
            for (int dz = -1; dz <= 1; ++dz) {
                int nz = z + dz;
                if ((unsigned)nz >= ZD) continue;
                int rowbase = ((nx * YD + ny) * ZD + nz) * TD + base_b;
                int kbase = (((dx + 1) * 3 + (dy + 1)) * 3 + (dz + 1)) * 3;
                for (int dt = -1; dt <= 1; ++dt) {
                    int nt = t + dt;
                    if ((unsigned)nt >= TD) continue;
                    int nlin = rowbase + nt;
                    if ((occ[nlin >> 5] >> (nlin & 31)) & 1u) {
                        const float* w = &w0s[(kbase + dt + 1) * CMID];
#pragma unroll
                        for (int c = 0; c < CMID; ++c) h[c] += w[c];
                    }
                }
            }
        }
    }

    float o = 0.0f;
#pragma unroll
    for (int c = 0; c < CMID; ++c) {
        float hc = 0.5f * h[c] + b0s[c];      // conv + b0 (mask==1 here)
        hc = hc > 0.0f ? hc : 0.0f;           // relu
        o += hc * w1s[c];
    }
    out[idx] = o + b1s;                       // (h @ W1 + b1) * mask, mask==1
}

extern "C" void kernel_launch(void* const* d_in, const int* in_sizes, int n_in,
                              void* d_out, int out_size, void* d_ws, size_t ws_size,
                              hipStream_t stream) {
    const float4* pts = (const float4*)d_in[0];   // (B, N, 4) fp32
    const float* W0   = (const float*)d_in[1];    // (81, 1, 8)
    const float* b0   = (const float*)d_in[2];    // (8,)
    const float* W1   = (const float*)d_in[3];    // (8, 1)
    const float* b1   = (const float*)d_in[4];    // (1,)
    float* out = (float*)d_out;
    unsigned int* occ = (unsigned int*)d_ws;      // 1.31 MB bitfield

    // Zero the occupancy bitfield every call (ws is poisoned / stale).
    hipMemsetAsync(occ, 0, OCC_WORDS * sizeof(unsigned int), stream);

    int npts = BD * NP;
    scatter_occ_kernel<<<(npts + 255) / 256, 256, 0, stream>>>(pts, occ);

    conv_kernel<<<NVOX / 256, 256, 0, stream>>>(occ, W0, b0, W1, b1, out);
}

// Round 2
// 163.379 us; speedup vs baseline: 1.9134x; 1.9134x over previous
//
#include <hip/hip_runtime.h>

// Problem constants (match reference)
#define XD 256
#define YD 256
#define ZD 16
#define TD 5
#define BD 2
#define NP 300000
#define CMID 8
#define VPB (XD * YD * ZD * TD)        // 5,242,880 voxels per batch
#define NVOX (BD * VPB)                // 10,485,760 total voxels
#define MAXPTS (BD * NP)               // 600,000
// Occupancy layout: 8 bits per (b,x,y,z) row (t in bits 0..4, 3 pad bits).
// idx8 = (b<<23)|(x<<15)|(y<<7)|(z<<3)|t  -> all power-of-2 decode.
#define OCC_BYTES (BD * XD * YD * ZD)  // 2,097,152 B = 2 MiB (L2-resident)
#define OCC_U32   (OCC_BYTES / 4)      // 524,288 words

// Workspace layout:
//   [0, 64):                counter (u32 at offset 0)
//   [64, 64+OCC_BYTES):     occupancy bitfield (16B-aligned for uint4 loads)
//   [64+OCC_BYTES, ...):    compacted occupied-voxel list (<= MAXPTS u32)

// ---------------------------------------------------------------------------
// Kernel 1: scatter points -> bit-packed occupancy (t-padded layout)
// ---------------------------------------------------------------------------
__global__ __launch_bounds__(256) void scatter_occ_kernel(
    const float4* __restrict__ pts, unsigned int* __restrict__ occ) {
    int i = blockIdx.x * 256 + threadIdx.x;
    if (i >= MAXPTS) return;
    float4 p = pts[i];
    // Match JAX exactly: floor(p / quant) (fp32 division by 0.4f), then clip.
    int cx = min(max((int)floorf(p.x / 0.4f), 0), XD - 1);
    int cy = min(max((int)floorf(p.y / 0.4f), 0), YD - 1);
    int cz = min(max((int)floorf(p.z / 0.4f), 0), ZD - 1);
    int ct = min(max((int)floorf(p.w / 1.0f), 0), TD - 1);
    int b  = i / NP;
    unsigned idx8 = ((unsigned)b << 23) | ((unsigned)cx << 15) |
                    ((unsigned)cy << 7) | ((unsigned)cz << 3) | (unsigned)ct;
    atomicOr(&occ[idx8 >> 5], 1u << (idx8 & 31));  // idempotent -> deterministic
}

// ---------------------------------------------------------------------------
// Kernel 2: stream-compact occupied voxel ids out of the bitfield
// ---------------------------------------------------------------------------
__global__ __launch_bounds__(256) void compact_kernel(
    const unsigned int* __restrict__ occ,
    unsigned int* __restrict__ count,
    unsigned int* __restrict__ list) {
    int j = blockIdx.x * 256 + threadIdx.x;  // grid covers OCC_U32 exactly
    unsigned w = occ[j];
    if (!w) return;
    unsigned pos = atomicAdd(count, (unsigned)__popc(w));  // wave-aggregated by compiler
    unsigned base = (unsigned)j * 32u;
    while (w) {
        int bit = __ffs(w) - 1;
        list[pos++] = base + (unsigned)bit;
        w &= w - 1;
    }
}

// ---------------------------------------------------------------------------
// Kernel 3: per-OCCUPIED-voxel 81-tap conv + ReLU + 8->1 projection.
// Unoccupied voxels are zeroed by the d_out memset (mask gating).
// ---------------------------------------------------------------------------
__global__ __launch_bounds__(256) void conv_kernel(
    const unsigned long long* __restrict__ occ64,  // bitfield viewed as u64[2] columns
    const unsigned int* __restrict__ count,
    const unsigned int* __restrict__ list,
    const float* __restrict__ W0,   // (81, 1, 8)
    const float* __restrict__ b0,   // (8)
    const float* __restrict__ W1,   // (8, 1)
    const float* __restrict__ b1,   // (1)
    float* __restrict__ out) {
    __shared__ float w0s[81 * CMID];
    __shared__ float b0s[CMID];
    __shared__ float w1s[CMID];
    __shared__ float b1s;
    for (int j = threadIdx.x; j < 81 * CMID; j += 256) w0s[j] = W0[j];
    if (threadIdx.x < CMID) {
        b0s[threadIdx.x] = b0[threadIdx.x];
        w1s[threadIdx.x] = W1[threadIdx.x];
    }
    if (threadIdx.x == 0) b1s = b1[0];
    __syncthreads();

    unsigned cnt = count[0];
    unsigned i = blockIdx.x * 256 + threadIdx.x;
    if (i >= cnt) return;

    unsigned idx8 = list[i];
    int t = idx8 & 7;
    int z = (idx8 >> 3) & 15;
    int y = (idx8 >> 7) & 255;
    int x = (idx8 >> 15) & 255;
    int b = (idx8 >> 23) & 1;

    float h[CMID];
#pragma unroll
    for (int c = 0; c < CMID; ++c) h[c] = 0.0f;

    // k = (((dx+1)*3 + (dy+1))*3 + (dz+1))*3 + (dt+1)  (ref accumulation order)
    for (int dx = -1; dx <= 1; ++dx) {
        int nx = x + dx;
        if ((unsigned)nx >= XD) continue;
        for (int dy = -1; dy <= 1; ++dy) {
            int ny = y + dy;
            if ((unsigned)ny >= YD) continue;
            // 16-byte z-column for (b,nx,ny): bytes z=0..15, loaded as 2x u64.
            int colidx = (b << 16) + (nx << 8) + ny;   // *16B = byte offset
            unsigned long long clo = occ64[2 * colidx + 0];  // z 0..7
            unsigned long long chi = occ64[2 * colidx + 1];  // z 8..15
            int kxy = ((dx + 1) * 3 + (dy + 1)) * 9;
#pragma unroll
            for (int dz = -1; dz <= 1; ++dz) {
                int nz = z + dz;
                if ((unsigned)nz >= ZD) continue;
                unsigned r = (unsigned)((nz < 8 ? (clo >> (nz * 8))
                                                : (chi >> ((nz - 8) * 8))) & 0xffull);
                if (!r) continue;
                int kb = kxy + (dz + 1) * 3;
#pragma unroll
                for (int dt = -1; dt <= 1; ++dt) {
                    int nt = t + dt;
                    if ((unsigned)nt < TD && ((r >> nt) & 1u)) {
                        const float* w = &w0s[(kb + dt + 1) * CMID];
#pragma unroll
                        for (int c = 0; c < CMID; ++c) h[c] += w[c];
                    }
                }
            }
        }
    }

    float o = 0.0f;
#pragma unroll
    for (int c = 0; c < CMID; ++c) {
        float hc = 0.5f * h[c] + b0s[c];   // grid value is exactly 0.5 at occupied
        hc = hc > 0.0f ? hc : 0.0f;        // relu
        o += hc * w1s[c];
    }
    int out_lin = (((x * YD + y) * ZD + z) * TD + t) + b * VPB;
    out[out_lin] = o + b1s;
}

extern "C" void kernel_launch(void* const* d_in, const int* in_sizes, int n_in,
                              void* d_out, int out_size, void* d_ws, size_t ws_size,
                              hipStream_t stream) {
    const float4* pts = (const float4*)d_in[0];
    const float* W0   = (const float*)d_in[1];
    const float* b0   = (const float*)d_in[2];
    const float* W1   = (const float*)d_in[3];
    const float* b1   = (const float*)d_in[4];
    float* out = (float*)d_out;

    unsigned int* cnt  = (unsigned int*)d_ws;
    unsigned int* occ  = (unsigned int*)((char*)d_ws + 64);
    unsigned int* list = (unsigned int*)((char*)d_ws + 64 + OCC_BYTES);

    // Zero counter + occupancy bitfield; zero the dense output (mask gating).
    hipMemsetAsync(d_ws, 0, 64 + OCC_BYTES, stream);
    hipMemsetAsync(d_out, 0, (size_t)NVOX * sizeof(float), stream);

    scatter_occ_kernel<<<(MAXPTS + 255) / 256, 256, 0, stream>>>(pts, occ);
    compact_kernel<<<OCC_U32 / 256, 256, 0, stream>>>(occ, cnt, list);
    conv_kernel<<<(MAXPTS + 255) / 256, 256, 0, stream>>>(
        (const unsigned long long*)occ, cnt, list, W0, b0, W1, b1, out);
}

// Round 3
// 79.572 us; speedup vs baseline: 3.9286x; 2.0532x over previous
//
#include <hip/hip_runtime.h>

// Problem constants (match reference)
#define XD 256
#define YD 256
#define ZD 16
#define TD 5
#define BD 2
#define NP 300000
#define CMID 8
#define VPB (XD * YD * ZD * TD)        // 5,242,880 voxels per batch
#define NVOX (BD * VPB)                // 10,485,760 total voxels
#define MAXPTS (BD * NP)               // 600,000
// Occupancy layout: 8 bits per (b,x,y,z) column entry (t in bits 0..4).
// idx8 = (b<<23)|(x<<15)|(y<<7)|(z<<3)|t  -> all power-of-2 decode.
#define OCC_BYTES (BD * XD * YD * ZD)  // 2 MiB (L2-resident)

// ---------------------------------------------------------------------------
// Kernel 1: scatter points -> bit-packed occupancy (t-padded layout)
// ---------------------------------------------------------------------------
__global__ __launch_bounds__(256) void scatter_occ_kernel(
    const float4* __restrict__ pts, unsigned int* __restrict__ occ) {
    int i = blockIdx.x * 256 + threadIdx.x;
    if (i >= MAXPTS) return;
    float4 p = pts[i];
    // Match JAX exactly: floor(p / quant) (fp32 division), then clip.
    int cx = min(max((int)floorf(p.x / 0.4f), 0), XD - 1);
    int cy = min(max((int)floorf(p.y / 0.4f), 0), YD - 1);
    int cz = min(max((int)floorf(p.z / 0.4f), 0), ZD - 1);
    int ct = min(max((int)floorf(p.w / 1.0f), 0), TD - 1);
    int b  = i / NP;
    unsigned idx8 = ((unsigned)b << 23) | ((unsigned)cx << 15) |
                    ((unsigned)cy << 7) | ((unsigned)cz << 3) | (unsigned)ct;
    atomicOr(&occ[idx8 >> 5], 1u << (idx8 & 31));  // idempotent -> deterministic
}

// ---------------------------------------------------------------------------
// Kernel 2: per-POINT 81-tap conv + ReLU + 8->1 projection at that point's
// voxel. Duplicate points in a voxel compute identical values and write the
// same address (benign race -> deterministic). Unoccupied voxels are zeroed
// by the d_out memset (mask gating).
// ---------------------------------------------------------------------------
__global__ __launch_bounds__(256) void conv_kernel(
    const float4* __restrict__ pts,
    const unsigned long long* __restrict__ occ64,  // bitfield as u64[2] z-columns
    const float* __restrict__ W0,   // (81, 1, 8)
    const float* __restrict__ b0,   // (8)
    const float* __restrict__ W1,   // (8, 1)
    const float* __restrict__ b1,   // (1)
    float* __restrict__ out) {
    __shared__ float w0s[81 * CMID];
    __shared__ float b0s[CMID];
    __shared__ float w1s[CMID];
    __shared__ float b1s;
    for (int j = threadIdx.x; j < 81 * CMID; j += 256) w0s[j] = W0[j];
    if (threadIdx.x < CMID) {
        b0s[threadIdx.x] = b0[threadIdx.x];
        w1s[threadIdx.x] = W1[threadIdx.x];
    }
    if (threadIdx.x == 0) b1s = b1[0];
    __syncthreads();

    int i = blockIdx.x * 256 + threadIdx.x;
    if (i >= MAXPTS) return;

    float4 p = pts[i];
    int x = min(max((int)floorf(p.x / 0.4f), 0), XD - 1);
    int y = min(max((int)floorf(p.y / 0.4f), 0), YD - 1);
    int z = min(max((int)floorf(p.z / 0.4f), 0), ZD - 1);
    int t = min(max((int)floorf(p.w / 1.0f), 0), TD - 1);
    int b = i / NP;

    float h[CMID];
#pragma unroll
    for (int c = 0; c < CMID; ++c) h[c] = 0.0f;

    // k = (((dx+1)*3 + (dy+1))*3 + (dz+1))*3 + (dt+1)  (ref accumulation order)
    for (int dx = -1; dx <= 1; ++dx) {
        int nx = x + dx;
        if ((unsigned)nx >= XD) continue;
        for (int dy = -1; dy <= 1; ++dy) {
            int ny = y + dy;
            if ((unsigned)ny >= YD) continue;
            // 16-byte z-column for (b,nx,ny): bytes z=0..15, as 2x u64.
            int colidx = (b << 16) + (nx << 8) + ny;
            unsigned long long clo = occ64[2 * colidx + 0];  // z 0..7
            unsigned long long chi = occ64[2 * colidx + 1];  // z 8..15
            int kxy = ((dx + 1) * 3 + (dy + 1)) * 9;
#pragma unroll
            for (int dz = -1; dz <= 1; ++dz) {
                int nz = z + dz;
                if ((unsigned)nz >= ZD) continue;
                unsigned r = (unsigned)((nz < 8 ? (clo >> (nz * 8))
                                                : (chi >> ((nz - 8) * 8))) & 0xffull);
                if (!r) continue;
                int kb = kxy + (dz + 1) * 3;
#pragma unroll
                for (int dt = -1; dt <= 1; ++dt) {
                    int nt = t + dt;
                    if ((unsigned)nt < TD && ((r >> nt) & 1u)) {
                        const float* w = &w0s[(kb + dt + 1) * CMID];
#pragma unroll
                        for (int c = 0; c < CMID; ++c) h[c] += w[c];
                    }
                }
            }
        }
    }

    float o = 0.0f;
#pragma unroll
    for (int c = 0; c < CMID; ++c) {
        float hc = 0.5f * h[c] + b0s[c];   // grid value is exactly 0.5 at occupied
        hc = hc > 0.0f ? hc : 0.0f;        // relu
        o += hc * w1s[c];
    }
    int out_lin = (((x * YD + y) * ZD + z) * TD + t) + b * VPB;
    out[out_lin] = o + b1s;
}

extern "C" void kernel_launch(void* const* d_in, const int* in_sizes, int n_in,
                              void* d_out, int out_size, void* d_ws, size_t ws_size,
                              hipStream_t stream) {
    const float4* pts = (const float4*)d_in[0];
    const float* W0   = (const float*)d_in[1];
    const float* b0   = (const float*)d_in[2];
    const float* W1   = (const float*)d_in[3];
    const float* b1   = (const float*)d_in[4];
    float* out = (float*)d_out;
    unsigned int* occ = (unsigned int*)d_ws;   // 2 MiB bitfield

    // Zero occupancy bitfield; zero the dense output (mask gating).
    hipMemsetAsync(occ, 0, OCC_BYTES, stream);
    hipMemsetAsync(d_out, 0, (size_t)NVOX * sizeof(float), stream);

    scatter_occ_kernel<<<(MAXPTS + 255) / 256, 256, 0, stream>>>(pts, occ);
    conv_kernel<<<(MAXPTS + 255) / 256, 256, 0, stream>>>(
        pts, (const unsigned long long*)occ, W0, b0, W1, b1, out);
}

// Round 4
// 75.458 us; speedup vs baseline: 4.1428x; 1.0545x over previous
//
#include <hip/hip_runtime.h>

// Problem constants (match reference)
#define XD 256
#define YD 256
#define ZD 16
#define TD 5
#define BD 2
#define NP 300000
#define CMID 8
#define VPB (XD * YD * ZD * TD)        // 5,242,880 voxels per batch
#define NVOX (BD * VPB)                // 10,485,760 total voxels
#define MAXPTS (BD * NP)               // 600,000
// Occupancy layout: 8 bits per (b,x,y,z) column entry (t in bits 0..4).
// idx8 = (b<<23)|(x<<15)|(y<<7)|(z<<3)|t  -> all power-of-2 decode.
#define OCC_BYTES (BD * XD * YD * ZD)  // 2 MiB (L2-resident)
#define OCC_U128  (OCC_BYTES / 16)     // 131,072 uint4
#define OUT_F4    (NVOX / 4)           // 2,621,440 float4

// ---------------------------------------------------------------------------
// Kernel 0: zero occupancy bitfield + dense output with wide stores.
// (runtime fillBuffer only hit ~1 TB/s at 8% occupancy; this hits write BW)
// ---------------------------------------------------------------------------
__global__ __launch_bounds__(256) void zero_kernel(
    uint4* __restrict__ occ, float4* __restrict__ out) {
    int i = blockIdx.x * 256 + threadIdx.x;
    int stride = gridDim.x * 256;
    uint4 zu = {0u, 0u, 0u, 0u};
    for (int j = i; j < OCC_U128; j += stride) occ[j] = zu;
    float4 zf = {0.f, 0.f, 0.f, 0.f};
    for (int j = i; j < OUT_F4; j += stride) out[j] = zf;
}

// ---------------------------------------------------------------------------
// Kernel 1: scatter points -> bit-packed occupancy (t-padded layout)
// ---------------------------------------------------------------------------
__global__ __launch_bounds__(256) void scatter_occ_kernel(
    const float4* __restrict__ pts, unsigned int* __restrict__ occ) {
    int i = blockIdx.x * 256 + threadIdx.x;
    if (i >= MAXPTS) return;
    float4 p = pts[i];
    // Match JAX exactly: floor(p / quant) (fp32 division), then clip.
    int cx = min(max((int)floorf(p.x / 0.4f), 0), XD - 1);
    int cy = min(max((int)floorf(p.y / 0.4f), 0), YD - 1);
    int cz = min(max((int)floorf(p.z / 0.4f), 0), ZD - 1);
    int ct = min(max((int)floorf(p.w / 1.0f), 0), TD - 1);
    int b  = i / NP;
    unsigned idx8 = ((unsigned)b << 23) | ((unsigned)cx << 15) |
                    ((unsigned)cy << 7) | ((unsigned)cz << 3) | (unsigned)ct;
    atomicOr(&occ[idx8 >> 5], 1u << (idx8 & 31));  // idempotent -> deterministic
}

// ---------------------------------------------------------------------------
// Kernel 2: per-POINT 81-tap conv + ReLU + 8->1 projection at that point's
// voxel. Duplicate points in a voxel compute identical values and write the
// same address (benign race -> deterministic). Unoccupied voxels are zeroed
// by zero_kernel (mask gating).
// ---------------------------------------------------------------------------
__global__ __launch_bounds__(256) void conv_kernel(
    const float4* __restrict__ pts,
    const unsigned long long* __restrict__ occ64,  // bitfield as u64[2] z-columns
    const float* __restrict__ W0,   // (81, 1, 8)
    const float* __restrict__ b0,   // (8)
    const float* __restrict__ W1,   // (8, 1)
    const float* __restrict__ b1,   // (1)
    float* __restrict__ out) {
    __shared__ float w0s[81 * CMID];
    __shared__ float b0s[CMID];
    __shared__ float w1s[CMID];
    __shared__ float b1s;
    for (int j = threadIdx.x; j < 81 * CMID; j += 256) w0s[j] = W0[j];
    if (threadIdx.x < CMID) {
        b0s[threadIdx.x] = b0[threadIdx.x];
        w1s[threadIdx.x] = W1[threadIdx.x];
    }
    if (threadIdx.x == 0) b1s = b1[0];
    __syncthreads();

    int i = blockIdx.x * 256 + threadIdx.x;
    if (i >= MAXPTS) return;

    float4 p = pts[i];
    int x = min(max((int)floorf(p.x / 0.4f), 0), XD - 1);
    int y = min(max((int)floorf(p.y / 0.4f), 0), YD - 1);
    int z = min(max((int)floorf(p.z / 0.4f), 0), ZD - 1);
    int t = min(max((int)floorf(p.w / 1.0f), 0), TD - 1);
    int b = i / NP;

    float h[CMID];
#pragma unroll
    for (int c = 0; c < CMID; ++c) h[c] = 0.0f;

    // k = (((dx+1)*3 + (dy+1))*3 + (dz+1))*3 + (dt+1)  (ref accumulation order)
    for (int dx = -1; dx <= 1; ++dx) {
        int nx = x + dx;
        if ((unsigned)nx >= XD) continue;
        for (int dy = -1; dy <= 1; ++dy) {
            int ny = y + dy;
            if ((unsigned)ny >= YD) continue;
            // 16-byte z-column for (b,nx,ny): bytes z=0..15, as 2x u64.
            int colidx = (b << 16) + (nx << 8) + ny;
            unsigned long long clo = occ64[2 * colidx + 0];  // z 0..7
            unsigned long long chi = occ64[2 * colidx + 1];  // z 8..15
            int kxy = ((dx + 1) * 3 + (dy + 1)) * 9;
#pragma unroll
            for (int dz = -1; dz <= 1; ++dz) {
                int nz = z + dz;
                if ((unsigned)nz >= ZD) continue;
                unsigned r = (unsigned)((nz < 8 ? (clo >> (nz * 8))
                                                : (chi >> ((nz - 8) * 8))) & 0xffull);
                if (!r) continue;
                int kb = kxy + (dz + 1) * 3;
#pragma unroll
                for (int dt = -1; dt <= 1; ++dt) {
                    int nt = t + dt;
                    if ((unsigned)nt < TD && ((r >> nt) & 1u)) {
                        const float* w = &w0s[(kb + dt + 1) * CMID];
#pragma unroll
                        for (int c = 0; c < CMID; ++c) h[c] += w[c];
                    }
                }
            }
        }
    }

    float o = 0.0f;
#pragma unroll
    for (int c = 0; c < CMID; ++c) {
        float hc = 0.5f * h[c] + b0s[c];   // grid value is exactly 0.5 at occupied
        hc = hc > 0.0f ? hc : 0.0f;        // relu
        o += hc * w1s[c];
    }
    int out_lin = (((x * YD + y) * ZD + z) * TD + t) + b * VPB;
    out[out_lin] = o + b1s;
}

extern "C" void kernel_launch(void* const* d_in, const int* in_sizes, int n_in,
                              void* d_out, int out_size, void* d_ws, size_t ws_size,
                              hipStream_t stream) {
    const float4* pts = (const float4*)d_in[0];
    const float* W0   = (const float*)d_in[1];
    const float* b0   = (const float*)d_in[2];
    const float* W1   = (const float*)d_in[3];
    const float* b1   = (const float*)d_in[4];
    float* out = (float*)d_out;
    unsigned int* occ = (unsigned int*)d_ws;   // 2 MiB bitfield

    // Zero occ + dense output at full write BW (mask gating).
    zero_kernel<<<2048, 256, 0, stream>>>((uint4*)occ, (float4*)out);

    scatter_occ_kernel<<<(MAXPTS + 255) / 256, 256, 0, stream>>>(pts, occ);
    conv_kernel<<<(MAXPTS + 255) / 256, 256, 0, stream>>>(
        pts, (const unsigned long long*)occ, W0, b0, W1, b1, out);
}

// Round 5
// 67.123 us; speedup vs baseline: 4.6573x; 1.1242x over previous
//
#include <hip/hip_runtime.h>

// Problem constants (match reference)
#define XD 256
#define YD 256
#define ZD 16
#define TD 5
#define BD 2
#define NP 300000
#define CMID 8
#define VPB (XD * YD * ZD * TD)        // 5,242,880 voxels per batch
#define NVOX (BD * VPB)                // 10,485,760 total voxels
#define MAXPTS (BD * NP)               // 600,000
// Occupancy layout: 8 bits per (b,x,y,z) cell (t occupies bits 0..4).
// idx8 = (b<<23)|(x<<15)|(y<<7)|(z<<3)|t  -> all power-of-2 decode.
#define OCC_BYTES (BD * XD * YD * ZD)  // 2 MiB (L2-resident)
#define OCC_U128  (OCC_BYTES / 16)     // 131,072 16B columns
#define OUT_F4    (NVOX / 4)           // 2,621,440 float4

#define SCAT_BLOCKS ((MAXPTS + 255) / 256)   // 2344
#define ZOUT_BLOCKS 2048

// ---------------------------------------------------------------------------
// Kernel 0: zero the 2 MiB occupancy bitfield (must precede scatter).
// ---------------------------------------------------------------------------
__global__ __launch_bounds__(256) void zero_occ_kernel(uint4* __restrict__ occ) {
    int i = blockIdx.x * 256 + threadIdx.x;
    uint4 z = {0u, 0u, 0u, 0u};
    for (int j = i; j < OCC_U128; j += 256 * 256) occ[j] = z;
}

// ---------------------------------------------------------------------------
// Kernel 1: fused [point scatter -> occupancy bits] || [zero dense output].
// Disjoint arrays -> no intra-kernel ordering hazard.
// ---------------------------------------------------------------------------
__global__ __launch_bounds__(256) void scatter_zero_kernel(
    const float4* __restrict__ pts, unsigned int* __restrict__ occ,
    float4* __restrict__ out4) {
    int blk = blockIdx.x;
    if (blk < SCAT_BLOCKS) {
        int i = blk * 256 + threadIdx.x;
        if (i >= MAXPTS) return;
        float4 p = pts[i];
        // Match JAX exactly: floor(p / quant) (fp32 division), then clip.
        int cx = min(max((int)floorf(p.x / 0.4f), 0), XD - 1);
        int cy = min(max((int)floorf(p.y / 0.4f), 0), YD - 1);
        int cz = min(max((int)floorf(p.z / 0.4f), 0), ZD - 1);
        int ct = min(max((int)floorf(p.w / 1.0f), 0), TD - 1);
        int b  = i / NP;
        unsigned idx8 = ((unsigned)b << 23) | ((unsigned)cx << 15) |
                        ((unsigned)cy << 7) | ((unsigned)cz << 3) | (unsigned)ct;
        atomicOr(&occ[idx8 >> 5], 1u << (idx8 & 31));  // idempotent
    } else {
        int i = (blk - SCAT_BLOCKS) * 256 + threadIdx.x;
        float4 z = {0.f, 0.f, 0.f, 0.f};
        for (int j = i; j < OUT_F4; j += ZOUT_BLOCKS * 256) out4[j] = z;
    }
}

// ---------------------------------------------------------------------------
// Kernel 2: per-POINT branchless conv + ReLU + 8->1 projection.
// tab[(p3*3+dzi)*8 + m] = sum over set bits of m (dt order) of W0 rows; rows
// padded to 12 floats (48 B, 16B-aligned) so random-row ds_read_b128 spreads
// across banks. m==0 rows are exactly 0.0f -> adding them is exact (h never
// becomes -0.0 from nonzero weights), so NO data-dependent branches at all.
// ---------------------------------------------------------------------------
__global__ __launch_bounds__(256) void conv_kernel(
    const float4* __restrict__ pts,
    const ulonglong2* __restrict__ occ128,  // 16B z-column per (b,x,y)
    const float* __restrict__ W0,   // (81, 1, 8)
    const float* __restrict__ b0,   // (8)
    const float* __restrict__ W1,   // (8, 1)
    const float* __restrict__ b1,   // (1)
    float* __restrict__ out) {
    __shared__ float tab[216 * 12];
    __shared__ float b0s[CMID];
    __shared__ float w1s[CMID];
    __shared__ float b1s;
    // Build mask-table: entry e = (kb in [0,27)) * 8 + (m in [0,8)).
    for (int e = threadIdx.x; e < 216; e += 256) {
        int kb = e >> 3;
        int m  = e & 7;
        float acc[CMID];
#pragma unroll
        for (int c = 0; c < CMID; ++c) acc[c] = 0.0f;
#pragma unroll
        for (int dti = 0; dti < 3; ++dti) {
            if ((m >> dti) & 1) {
                const float* w = &W0[(kb * 3 + dti) * CMID];
#pragma unroll
                for (int c = 0; c < CMID; ++c) acc[c] += w[c];
            }
        }
#pragma unroll
        for (int c = 0; c < CMID; ++c) tab[e * 12 + c] = acc[c];
    }
    if (threadIdx.x < CMID) {
        b0s[threadIdx.x] = b0[threadIdx.x];
        w1s[threadIdx.x] = W1[threadIdx.x];
    }
    if (threadIdx.x == 0) b1s = b1[0];
    __syncthreads();

    int i = blockIdx.x * 256 + threadIdx.x;
    if (i >= MAXPTS) return;

    float4 p = pts[i];
    int x = min(max((int)floorf(p.x / 0.4f), 0), XD - 1);
    int y = min(max((int)floorf(p.y / 0.4f), 0), YD - 1);
    int z = min(max((int)floorf(p.z / 0.4f), 0), ZD - 1);
    int t = min(max((int)floorf(p.w / 1.0f), 0), TD - 1);
    int b = i / NP;

    float h[CMID];
#pragma unroll
    for (int c = 0; c < CMID; ++c) h[c] = 0.0f;

#pragma unroll
    for (int dxi = 0; dxi < 3; ++dxi) {
        int nx = x + dxi - 1;
#pragma unroll
        for (int dyi = 0; dyi < 3; ++dyi) {
            int ny = y + dyi - 1;
            int valid = ((unsigned)nx < XD) && ((unsigned)ny < YD);
            int colidx = (b << 16) | ((nx & 255) << 8) | (ny & 255);
            ulonglong2 col = occ128[colidx];           // safe addr even if !valid
            unsigned long long clo = valid ? col.x : 0ull;  // z 0..7
            unsigned long long chi = valid ? col.y : 0ull;  // z 8..15
            int p3 = (dxi * 3 + dyi) * 3;
#pragma unroll
            for (int dzi = 0; dzi < 3; ++dzi) {
                int nz = z + dzi - 1;
                unsigned r = (unsigned)((nz < 8 ? (clo >> (nz * 8))
                                                : (chi >> ((nz - 8) * 8))) & 0xffull);
                r = ((unsigned)nz < ZD) ? r : 0u;
                unsigned m = ((r << 1) >> t) & 7u;     // bits t-1,t,t+1 of r
                const float4* row = (const float4*)&tab[((p3 + dzi) * 8 + m) * 12];
                float4 ta = row[0];
                float4 tb = row[1];
                h[0] += ta.x; h[1] += ta.y; h[2] += ta.z; h[3] += ta.w;
                h[4] += tb.x; h[5] += tb.y; h[6] += tb.z; h[7] += tb.w;
            }
        }
    }

    float o = 0.0f;
#pragma unroll
    for (int c = 0; c < CMID; ++c) {
        float hc = 0.5f * h[c] + b0s[c];   // grid value is exactly 0.5 at occupied
        hc = hc > 0.0f ? hc : 0.0f;        // relu
        o += hc * w1s[c];
    }
    int out_lin = (((x * YD + y) * ZD + z) * TD + t) + b * VPB;
    out[out_lin] = o + b1s;
}

extern "C" void kernel_launch(void* const* d_in, const int* in_sizes, int n_in,
                              void* d_out, int out_size, void* d_ws, size_t ws_size,
                              hipStream_t stream) {
    const float4* pts = (const float4*)d_in[0];
    const float* W0   = (const float*)d_in[1];
    const float* b0   = (const float*)d_in[2];
    const float* W1   = (const float*)d_in[3];
    const float* b1   = (const float*)d_in[4];
    float* out = (float*)d_out;
    unsigned int* occ = (unsigned int*)d_ws;   // 2 MiB bitfield

    zero_occ_kernel<<<256, 256, 0, stream>>>((uint4*)occ);
    scatter_zero_kernel<<<SCAT_BLOCKS + ZOUT_BLOCKS, 256, 0, stream>>>(
        pts, occ, (float4*)out);
    conv_kernel<<<SCAT_BLOCKS, 256, 0, stream>>>(
        pts, (const ulonglong2*)occ, W0, b0, W1, b1, out);
}

// Round 6
// 63.482 us; speedup vs baseline: 4.9244x; 1.0573x over previous
//
#include <hip/hip_runtime.h>

// Problem constants (match reference)
#define XD 256
#define YD 256
#define ZD 16
#define TD 5
#define BD 2
#define NP 300000
#define CMID 8
#define VPB (XD * YD * ZD * TD)        // 5,242,880 voxels per batch
#define NVOX (BD * VPB)                // 10,485,760 total voxels
#define MAXPTS (BD * NP)               // 600,000
// Occupancy layout: 8 bits per (b,x,y,z) cell (t occupies bits 0..4).
// idx8 = (b<<23)|(x<<15)|(y<<7)|(z<<3)|t  -> all power-of-2 decode.
#define OCC_BYTES (BD * XD * YD * ZD)  // 2 MiB (L2-resident)
#define OCC_U128  (OCC_BYTES / 16)     // 131,072 16B columns
#define OUT_F4    (NVOX / 4)           // 2,621,440 float4

#define SCAT_BLOCKS ((MAXPTS + 255) / 256)   // 2344
#define ZOUT_BLOCKS 2048

// ---------------------------------------------------------------------------
// Kernel 0: zero the 2 MiB occupancy bitfield (must precede scatter).
// ---------------------------------------------------------------------------
__global__ __launch_bounds__(256) void zero_occ_kernel(uint4* __restrict__ occ) {
    int i = blockIdx.x * 256 + threadIdx.x;
    uint4 z = {0u, 0u, 0u, 0u};
    for (int j = i; j < OCC_U128; j += 512 * 256) occ[j] = z;
}

// ---------------------------------------------------------------------------
// Kernel 1: fused [point scatter -> occupancy bits] || [zero dense output].
// Disjoint arrays -> no intra-kernel ordering hazard.
// ---------------------------------------------------------------------------
__global__ __launch_bounds__(256) void scatter_zero_kernel(
    const float4* __restrict__ pts, unsigned int* __restrict__ occ,
    float4* __restrict__ out4) {
    int blk = blockIdx.x;
    if (blk < SCAT_BLOCKS) {
        int i = blk * 256 + threadIdx.x;
        if (i >= MAXPTS) return;
        float4 p = pts[i];
        // Match JAX exactly: floor(p / quant) (fp32 division), then clip.
        int cx = min(max((int)floorf(p.x / 0.4f), 0), XD - 1);
        int cy = min(max((int)floorf(p.y / 0.4f), 0), YD - 1);
        int cz = min(max((int)floorf(p.z / 0.4f), 0), ZD - 1);
        int ct = min(max((int)floorf(p.w / 1.0f), 0), TD - 1);
        int b  = i / NP;
        unsigned idx8 = ((unsigned)b << 23) | ((unsigned)cx << 15) |
                        ((unsigned)cy << 7) | ((unsigned)cz << 3) | (unsigned)ct;
        atomicOr(&occ[idx8 >> 5], 1u << (idx8 & 31));  // idempotent
    } else {
        int i = (blk - SCAT_BLOCKS) * 256 + threadIdx.x;
        float4 z = {0.f, 0.f, 0.f, 0.f};
        for (int j = i; j < OUT_F4; j += ZOUT_BLOCKS * 256) out4[j] = z;
    }
}

// ---------------------------------------------------------------------------
// Kernel 2: per-POINT conv + ReLU + 8->1 projection.
// tab[(p3*3+dzi)*8 + m] = sum over set bits of m (dt order) of W0 rows (rows
// padded to 12 floats). LDS reads + adds are exec-predicated on m!=0 (only
// ~16% of taps fire -> ~10/64 active lanes -> near-conflict-free LDS).
// All 9 neighbor columns prefetched into registers up front.
// ---------------------------------------------------------------------------
__global__ __launch_bounds__(256) void conv_kernel(
    const float4* __restrict__ pts,
    const ulonglong2* __restrict__ occ128,  // 16B z-column per (b,x,y)
    const float* __restrict__ W0,   // (81, 1, 8)
    const float* __restrict__ b0,   // (8)
    const float* __restrict__ W1,   // (8, 1)
    const float* __restrict__ b1,   // (1)
    float* __restrict__ out) {
    __shared__ float tab[216 * 12];
    __shared__ float b0s[CMID];
    __shared__ float w1s[CMID];
    __shared__ float b1s;
    // Build mask-table: entry e = (kb in [0,27)) * 8 + (m in [0,8)).
    for (int e = threadIdx.x; e < 216; e += 256) {
        int kb = e >> 3;
        int m  = e & 7;
        float acc[CMID];
#pragma unroll
        for (int c = 0; c < CMID; ++c) acc[c] = 0.0f;
#pragma unroll
        for (int dti = 0; dti < 3; ++dti) {
            if ((m >> dti) & 1) {
                const float* w = &W0[(kb * 3 + dti) * CMID];
#pragma unroll
                for (int c = 0; c < CMID; ++c) acc[c] += w[c];
            }
        }
#pragma unroll
        for (int c = 0; c < CMID; ++c) tab[e * 12 + c] = acc[c];
    }
    if (threadIdx.x < CMID) {
        b0s[threadIdx.x] = b0[threadIdx.x];
        w1s[threadIdx.x] = W1[threadIdx.x];
    }
    if (threadIdx.x == 0) b1s = b1[0];
    __syncthreads();

    int i = blockIdx.x * 256 + threadIdx.x;
    if (i >= MAXPTS) return;

    float4 p = pts[i];
    int x = min(max((int)floorf(p.x / 0.4f), 0), XD - 1);
    int y = min(max((int)floorf(p.y / 0.4f), 0), YD - 1);
    int z = min(max((int)floorf(p.z / 0.4f), 0), ZD - 1);
    int t = min(max((int)floorf(p.w / 1.0f), 0), TD - 1);
    int b = i / NP;

    // Prefetch the 9 neighbor z-columns (fully unrolled -> registers).
    unsigned long long clo[3][3], chi[3][3];
#pragma unroll
    for (int dxi = 0; dxi < 3; ++dxi) {
        int nx = x + dxi - 1;
#pragma unroll
        for (int dyi = 0; dyi < 3; ++dyi) {
            int ny = y + dyi - 1;
            bool valid = ((unsigned)nx < XD) && ((unsigned)ny < YD);
            int colidx = (b << 16) | ((nx & 255) << 8) | (ny & 255);
            ulonglong2 col = occ128[colidx];       // addr safe even if !valid
            clo[dxi][dyi] = valid ? col.x : 0ull;  // z 0..7
            chi[dxi][dyi] = valid ? col.y : 0ull;  // z 8..15
        }
    }

    float4 h0 = {0.f, 0.f, 0.f, 0.f};
    float4 h1 = {0.f, 0.f, 0.f, 0.f};

#pragma unroll
    for (int dxi = 0; dxi < 3; ++dxi) {
#pragma unroll
        for (int dyi = 0; dyi < 3; ++dyi) {
            unsigned long long lo = clo[dxi][dyi];
            unsigned long long hi = chi[dxi][dyi];
            int p3 = (dxi * 3 + dyi) * 3;
#pragma unroll
            for (int dzi = 0; dzi < 3; ++dzi) {
                int nz = z + dzi - 1;              // in [-1, 16]
                unsigned sh = ((unsigned)nz * 8u) & 63u;  // wrap-safe shift
                unsigned r = (unsigned)(((nz & 8) ? (hi >> sh) : (lo >> sh)) & 0xffull);
                r = ((unsigned)nz < ZD) ? r : 0u;
                unsigned m = ((r << 1) >> t) & 7u; // bits t-1,t,t+1 of r
                if (m) {                           // exec-predicated (~16% lanes)
                    const float4* row =
                        (const float4*)&tab[((p3 + dzi) * 8 + (int)m) * 12];
                    h0 += row[0];
                    h1 += row[1];
                }
            }
        }
    }

    float hc[CMID] = {h0.x, h0.y, h0.z, h0.w, h1.x, h1.y, h1.z, h1.w};
    float o = 0.0f;
#pragma unroll
    for (int c = 0; c < CMID; ++c) {
        float v = 0.5f * hc[c] + b0s[c];   // grid value is exactly 0.5 at occupied
        v = v > 0.0f ? v : 0.0f;           // relu
        o += v * w1s[c];
    }
    int out_lin = (((x * YD + y) * ZD + z) * TD + t) + b * VPB;
    out[out_lin] = o + b1s;
}

extern "C" void kernel_launch(void* const* d_in, const int* in_sizes, int n_in,
                              void* d_out, int out_size, void* d_ws, size_t ws_size,
                              hipStream_t stream) {
    const float4* pts = (const float4*)d_in[0];
    const float* W0   = (const float*)d_in[1];
    const float* b0   = (const float*)d_in[2];
    const float* W1   = (const float*)d_in[3];
    const float* b1   = (const float*)d_in[4];
    float* out = (float*)d_out;
    unsigned int* occ = (unsigned int*)d_ws;   // 2 MiB bitfield

    zero_occ_kernel<<<512, 256, 0, stream>>>((uint4*)occ);
    scatter_zero_kernel<<<SCAT_BLOCKS + ZOUT_BLOCKS, 256, 0, stream>>>(
        pts, occ, (float4*)out);
    conv_kernel<<<SCAT_BLOCKS, 256, 0, stream>>>(
        pts, (const ulonglong2*)occ, W0, b0, W1, b1, out);
}

// Round 7
// 59.319 us; speedup vs baseline: 5.2699x; 1.0702x over previous
//
#include <hip/hip_runtime.h>

// Problem constants (match reference)
#define XD 256
#define YD 256
#define ZD 16
#define TD 5
#define BD 2
#define NP 300000
#define CMID 8
#define VPB (XD * YD * ZD * TD)        // 5,242,880 voxels per batch
#define NVOX (BD * VPB)                // 10,485,760 total voxels
#define MAXPTS (BD * NP)               // 600,000
// Occupancy layout: 8 bits per (b,x,y,z) cell (t occupies bits 0..4).
// idx8 = (b<<23)|(x<<15)|(y<<7)|(z<<3)|t  -> all power-of-2 decode.
#define OCC_BYTES (BD * XD * YD * ZD)  // 2 MiB (L2-resident)
#define OCC_U128  (OCC_BYTES / 16)     // 131,072 16B columns
#define OUT_F4    (NVOX / 4)           // 2,621,440 float4

#define SCAT_BLOCKS ((MAXPTS + 255) / 256)   // 2344
#define ZOUT_BLOCKS 2048
#define CONV_BLOCKS 2048               // 131,072 columns / 64 per block

// ---------------------------------------------------------------------------
// Kernel 0: zero the 2 MiB occupancy bitfield (must precede scatter).
// ---------------------------------------------------------------------------
__global__ __launch_bounds__(256) void zero_occ_kernel(uint4* __restrict__ occ) {
    int i = blockIdx.x * 256 + threadIdx.x;
    uint4 z = {0u, 0u, 0u, 0u};
    for (int j = i; j < OCC_U128; j += 512 * 256) occ[j] = z;
}

// ---------------------------------------------------------------------------
// Kernel 1: fused [point scatter -> occupancy bits] || [zero dense output].
// Disjoint arrays -> no intra-kernel ordering hazard.
// ---------------------------------------------------------------------------
__global__ __launch_bounds__(256) void scatter_zero_kernel(
    const float4* __restrict__ pts, unsigned int* __restrict__ occ,
    float4* __restrict__ out4) {
    int blk = blockIdx.x;
    if (blk < SCAT_BLOCKS) {
        int i = blk * 256 + threadIdx.x;
        if (i >= MAXPTS) return;
        float4 p = pts[i];
        // Match JAX exactly: floor(p / quant) (fp32 division), then clip.
        int cx = min(max((int)floorf(p.x / 0.4f), 0), XD - 1);
        int cy = min(max((int)floorf(p.y / 0.4f), 0), YD - 1);
        int cz = min(max((int)floorf(p.z / 0.4f), 0), ZD - 1);
        int ct = min(max((int)floorf(p.w / 1.0f), 0), TD - 1);
        int b  = i / NP;
        unsigned idx8 = ((unsigned)b << 23) | ((unsigned)cx << 15) |
                        ((unsigned)cy << 7) | ((unsigned)cz << 3) | (unsigned)ct;
        atomicOr(&occ[idx8 >> 5], 1u << (idx8 & 31));  // idempotent
    } else {
        int i = (blk - SCAT_BLOCKS) * 256 + threadIdx.x;
        float4 z = {0.f, 0.f, 0.f, 0.f};
        for (int j = i; j < OUT_F4; j += ZOUT_BLOCKS * 256) out4[j] = z;
    }
}

// ---------------------------------------------------------------------------
// Kernel 2: strip-local conv. Block owns columns (b, x, ny0..ny0+63):
//   1. coalesced-load the 3x66 neighbor columns into LDS
//   2. block-local compaction of occupied slots into an LDS queue (scan)
//   3. threads round-robin queue entries: m-table conv + ReLU + 8->1 proj
// No global atomics; fully deterministic; all global loads coalesced.
// ---------------------------------------------------------------------------
__global__ __launch_bounds__(256) void conv_kernel(
    const ulonglong2* __restrict__ occ128,  // 16B z-column per (b,x,y)
    const float* __restrict__ W0,   // (81, 1, 8)
    const float* __restrict__ b0,   // (8)
    const float* __restrict__ W1,   // (8, 1)
    const float* __restrict__ b1,   // (1)
    float* __restrict__ out) {
    __shared__ float tab[216 * 12];
    __shared__ ulonglong2 cols[3][66];
    __shared__ unsigned short queue[64 * 80];
    __shared__ unsigned scan[256];
    __shared__ float b0s[CMID];
    __shared__ float w1s[CMID];
    __shared__ float b1s;

    int tid = threadIdx.x;
    int blk = blockIdx.x;
    int b   = blk >> 10;
    int x   = (blk >> 2) & 255;
    int ny0 = (blk & 3) << 6;

    // --- mask-table: entry e = kb[0,27) * 8 + m[0,8); rows padded to 12 ---
    for (int e = tid; e < 216; e += 256) {
        int kb = e >> 3;
        int m  = e & 7;
        float acc[CMID];
#pragma unroll
        for (int c = 0; c < CMID; ++c) acc[c] = 0.0f;
#pragma unroll
        for (int dti = 0; dti < 3; ++dti) {
            if ((m >> dti) & 1) {
                const float* w = &W0[(kb * 3 + dti) * CMID];
#pragma unroll
                for (int c = 0; c < CMID; ++c) acc[c] += w[c];
            }
        }
#pragma unroll
        for (int c = 0; c < CMID; ++c) tab[e * 12 + c] = acc[c];
    }
    if (tid < CMID) {
        b0s[tid] = b0[tid];
        w1s[tid] = W1[tid];
    }
    if (tid == 0) b1s = b1[0];

    // --- coalesced load of the 3x66 column neighborhood ---
    for (int j = tid; j < 3 * 66; j += 256) {
        int r   = j / 66;           // dxi
        int cyl = j % 66;           // local ny + 1
        int nx  = x + r - 1;
        int cy  = ny0 + cyl - 1;
        bool valid = ((unsigned)nx < XD) && ((unsigned)cy < YD);
        ulonglong2 col = occ128[(b << 16) | ((nx & 255) << 8) | (cy & 255)];
        ulonglong2 v;
        v.x = valid ? col.x : 0ull;
        v.y = valid ? col.y : 0ull;
        cols[r][cyl] = v;
    }
    __syncthreads();

    // --- block-local compaction: word tid of own 64 columns ---
    const unsigned* ownw = (const unsigned*)&cols[1][1];   // 256 contiguous u32
    unsigned w = ownw[tid];
    int cnt = __popc(w);

    scan[tid] = (unsigned)cnt;
    __syncthreads();
    for (int off = 1; off < 256; off <<= 1) {
        unsigned add = (tid >= off) ? scan[tid - off] : 0u;
        __syncthreads();
        scan[tid] += add;
        __syncthreads();
    }
    unsigned pos  = scan[tid] - (unsigned)cnt;   // exclusive prefix
    unsigned qlen = scan[255];

    {
        int cl = tid >> 2;          // column-in-block
        int zb = (tid & 3) << 2;    // z base of this word
        unsigned ww = w;
        while (ww) {
            int bi = __ffs(ww) - 1;
            ww &= ww - 1;
            int zz = zb + (bi >> 3);
            int tt = bi & 7;        // always < 5 (scatter sets only t<5)
            queue[pos++] = (unsigned short)((cl << 7) | (zz << 3) | tt);
        }
    }
    __syncthreads();

    // --- conv over compacted entries ---
    for (unsigned q = tid; q < qlen; q += 256) {
        int e  = queue[q];
        int cl = e >> 7;
        int z  = (e >> 3) & 15;
        int t  = e & 7;

        float4 h0 = {0.f, 0.f, 0.f, 0.f};
        float4 h1 = {0.f, 0.f, 0.f, 0.f};
#pragma unroll
        for (int dxi = 0; dxi < 3; ++dxi) {
#pragma unroll
            for (int dyi = 0; dyi < 3; ++dyi) {
                ulonglong2 col = cols[dxi][cl + dyi];   // LDS b128 read
                int p3 = (dxi * 3 + dyi) * 3;
#pragma unroll
                for (int dzi = 0; dzi < 3; ++dzi) {
                    int nz = z + dzi - 1;                     // in [-1, 16]
                    unsigned sh = ((unsigned)nz * 8u) & 63u;  // wrap-safe
                    unsigned r = (unsigned)(((nz & 8) ? (col.y >> sh)
                                                      : (col.x >> sh)) & 0xffull);
                    r = ((unsigned)nz < ZD) ? r : 0u;
                    unsigned m = ((r << 1) >> t) & 7u;  // bits t-1,t,t+1
                    if (m) {                            // ~16% of taps fire
                        const float4* row =
                            (const float4*)&tab[((p3 + dzi) * 8 + (int)m) * 12];
                        h0 += row[0];
                        h1 += row[1];
                    }
                }
            }
        }

        float hc[CMID] = {h0.x, h0.y, h0.z, h0.w, h1.x, h1.y, h1.z, h1.w};
        float o = 0.0f;
#pragma unroll
        for (int c = 0; c < CMID; ++c) {
            float v = 0.5f * hc[c] + b0s[c];   // grid value is exactly 0.5
            v = v > 0.0f ? v : 0.0f;           // relu
            o += v * w1s[c];
        }
        int yv = ny0 + cl;
        out[(((x * YD + yv) * ZD + z) * TD + t) + b * VPB] = o + b1s;
    }
}

extern "C" void kernel_launch(void* const* d_in, const int* in_sizes, int n_in,
                              void* d_out, int out_size, void* d_ws, size_t ws_size,
                              hipStream_t stream) {
    const float4* pts = (const float4*)d_in[0];
    const float* W0   = (const float*)d_in[1];
    const float* b0   = (const float*)d_in[2];
    const float* W1   = (const float*)d_in[3];
    const float* b1   = (const float*)d_in[4];
    float* out = (float*)d_out;
    unsigned int* occ = (unsigned int*)d_ws;   // 2 MiB bitfield

    zero_occ_kernel<<<512, 256, 0, stream>>>((uint4*)occ);
    scatter_zero_kernel<<<SCAT_BLOCKS + ZOUT_BLOCKS, 256, 0, stream>>>(
        pts, occ, (float4*)out);
    conv_kernel<<<CONV_BLOCKS, 256, 0, stream>>>(
        (const ulonglong2*)occ, W0, b0, W1, b1, out);
}